// Round 5
// baseline (282.753 us; speedup 1.0000x reference)
//
#include <hip/hip_runtime.h>
#include <math.h>

typedef short bf16x8 __attribute__((ext_vector_type(8)));
typedef float f32x16 __attribute__((ext_vector_type(16)));
typedef float f32x4  __attribute__((ext_vector_type(4)));
typedef float f32x2  __attribute__((ext_vector_type(2)));
typedef unsigned int u32x4 __attribute__((ext_vector_type(4)));

namespace {
constexpr int kNCont = 6, kNCat = 6, kNCategories = 100;
constexpr int kQ = 12, kD = 10, kHid = 20, kD0 = 10;
constexpr int kL1 = 30, kL2 = 20, kNPairs = 78;
constexpr int kM = 32;            // batch tile per block
constexpr int kBlock = 256;       // 4 waves
}

// Per-wave k ownership (partition of 0..11); pair counts 19/20/20/19.
__constant__ int cKset[12] = {11, 4, 1, 10, 5, 2, 9, 8, 0, 7, 6, 3};

union ABu { u32x4 u; bf16x8 s; unsigned int w[4]; unsigned short h[8]; };
union D16 { f32x16 v; f32x2 p[8]; float f[16]; };

__device__ __forceinline__ float uf(unsigned int x) { return __uint_as_float(x); }
__device__ __forceinline__ unsigned int fu(float x) { return __float_as_uint(x); }
__device__ __forceinline__ unsigned short f2bf_rne(float v) {
    unsigned int x = fu(v);
    return (unsigned short)((x + 0x7FFFu + ((x >> 16) & 1u)) >> 16);
}
// pack two f32 to bf16x2 by truncation (1 v_perm): lo16=hi(src1), hi16=hi(src0)
__device__ __forceinline__ unsigned int pack_trunc(float e0, float e1) {
    return __builtin_amdgcn_perm(fu(e1), fu(e0), 0x07060302u);
}

// bias[p][i] (i<30) = sb1[i] + tokens[p]@sW1[20:30]; i=30,31 -> 0.
// Slot [78*32]: out_b + sb3/6 * sum(out_w).
__global__ void pairbias_kernel(const float* __restrict__ tokens,
                                const float* __restrict__ sW1,
                                const float* __restrict__ sb1,
                                const float* __restrict__ sb3,
                                const float* __restrict__ out_w,
                                const float* __restrict__ out_b,
                                float* __restrict__ pairBias) {
    const int t = blockIdx.x * blockDim.x + threadIdx.x;
    if (t < kNPairs * 32) {
        const int p = t >> 5, i = t & 31;
        float val = 0.0f;
        if (i < kL1) {
            val = sb1[i];
            #pragma unroll
            for (int d = 0; d < kD0; ++d)
                val = fmaf(tokens[p * kD0 + d], sW1[(2 * kD + d) * kL1 + i], val);
        }
        pairBias[t] = val;
    } else if (t == kNPairs * 32) {
        float s = 0.0f;
        for (int p = 0; p < kNPairs; ++p) s += out_w[p];
        pairBias[t] = out_b[0] + sb3[0] * (1.0f / 6.0f) * s;
    }
}

// Embedding E[gb,q,:] as 5 f32x2. q is SCALAR.
__device__ __forceinline__ void compute_E(
    int q, int gb,
    const float* __restrict__ x_cont, const int* __restrict__ x_cat,
    const float* __restrict__ cont_W1, const float* __restrict__ cont_b1,
    const float* __restrict__ cont_W2, const float* __restrict__ cont_b2,
    const float* __restrict__ cat_tables, f32x2 E2[5])
{
    if (q < kNCont) {
        const float x = x_cont[gb * kNCont + q];
        #pragma unroll
        for (int dd = 0; dd < 5; ++dd)
            E2[dd] = f32x2{cont_b2[q * kD + 2 * dd], cont_b2[q * kD + 2 * dd + 1]};
        #pragma unroll
        for (int h = 0; h < kHid; ++h) {
            const float pre = fmaf(x, cont_W1[q * kHid + h], cont_b1[q * kHid + h]);
            const float hv  = fmaxf(pre, 0.0f);
            const f32x2 hv2 = {hv, hv};
            const float* w2 = cont_W2 + (q * kHid + h) * kD;
            #pragma unroll
            for (int dd = 0; dd < 5; ++dd)
                E2[dd] = __builtin_elementwise_fma(
                    hv2, f32x2{w2[2 * dd], w2[2 * dd + 1]}, E2[dd]);
        }
    } else {
        const int c   = q - kNCont;
        const int idx = x_cat[gb * kNCat + c];
        const float* src = cat_tables + (c * kNCategories + idx) * kD;
        #pragma unroll
        for (int dd = 0; dd < 5; ++dd)
            E2[dd] = f32x2{src[2 * dd], src[2 * dd + 1]};   // 8B-aligned (40B stride)
    }
}

// g2[0..14] = E @ W (30 outputs as 15 f32x2); g2[15] = {v30, 0}. W scalar ptr.
__device__ __forceinline__ void matvec30(const f32x2 E2[5],
                                         const float* __restrict__ W,
                                         f32x2 g2[16], float v30)
{
    #pragma unroll
    for (int ii = 0; ii < 15; ++ii) g2[ii] = f32x2{0.0f, 0.0f};
    #pragma unroll
    for (int d = 0; d < kD; ++d) {
        const float ed = (d & 1) ? E2[d >> 1].y : E2[d >> 1].x;
        const f32x2 ed2 = {ed, ed};
        const float* wr = W + d * kL1;
        #pragma unroll
        for (int ii = 0; ii < 15; ++ii)
            g2[ii] = __builtin_elementwise_fma(
                ed2, f32x2{wr[2 * ii], wr[2 * ii + 1]}, g2[ii]);
    }
    g2[15] = f32x2{v30, 0.0f};
}

__global__ __launch_bounds__(kBlock, 3) void pin_main(
    const float* __restrict__ x_cont,
    const int*   __restrict__ x_cat,
    const float* __restrict__ exposure,
    const float* __restrict__ cont_W1,
    const float* __restrict__ cont_b1,
    const float* __restrict__ cont_W2,
    const float* __restrict__ cont_b2,
    const float* __restrict__ cat_tables,
    const float* __restrict__ sW1,     // [30,30]
    const float* __restrict__ sW2,     // [30,20]
    const float* __restrict__ sb2,     // [20]
    const float* __restrict__ sW3,     // [20]
    const float* __restrict__ out_w,   // [78]
    const float* __restrict__ pairBias,// [78*32 + 1]
    float* __restrict__ out)
{
    // G f32, A-frag chunk layout: [j][cc=i/4][b][4 f32]; lane-contiguous b128.
    __shared__ float Glds[kQ * 8 * kM * 4];          // 49152 B
    __shared__ float etab[kM];                        // 128 B

    const int tid   = threadIdx.x;
    const int lane  = tid & 63;
    const int b     = lane & 31;          // batch row / MFMA col n
    const int ihalf = lane >> 5;          // fragment k-half selector
    const int wv    = __builtin_amdgcn_readfirstlane((int)(tid >> 6));
    const int gb    = blockIdx.x * kM + b;

    if (tid < kM) etab[tid] = 0.0f;

    // ---- B fragments (sW2 + sb2 ones-row), RNE once ----
    ABu bf0, bf1;
    #pragma unroll
    for (int e = 0; e < 8; ++e) {
        const int k0 = ihalf * 8 + e;
        const int k1 = 16 + ihalf * 8 + e;
        float v0 = 0.0f, v1 = 0.0f;
        if (b < kL2) {
            v0 = (k0 < kL1) ? sW2[k0 * kL2 + b] : (k0 == 30 ? sb2[b] : 0.0f);
            v1 = (k1 < kL1) ? sW2[k1 * kL2 + b] : (k1 == 30 ? sb2[b] : 0.0f);
        }
        bf0.h[e] = f2bf_rne(v0);
        bf1.h[e] = f2bf_rne(v1);
    }
    const float w3v6 = (b < kL2 ? sW3[b] : 0.0f) * (1.0f / 6.0f);

    // ---- Phase A: G[j] = E[j]@W1a (ones row at i=30) -> LDS f32 ----
    #pragma unroll 1
    for (int jj = 0; jj < 3; ++jj) {
        const int j = wv * 3 + jj;                        // scalar
        f32x2 E2[5];
        compute_E(j, gb, x_cont, x_cat, cont_W1, cont_b1, cont_W2, cont_b2,
                  cat_tables, E2);
        f32x2 g2[16];
        matvec30(E2, sW1, g2, 1.0f);                      // W1a rows 0..9
        // this half stores chunks cc = ihalf*4 .. +3 (i = 16*ihalf .. +15)
        #pragma unroll
        for (int c = 0; c < 4; ++c) {
            const int cc = ihalf * 4 + c;
            f32x4 gv = {g2[2 * cc].x, g2[2 * cc].y,
                        g2[2 * cc + 1].x, g2[2 * cc + 1].y};
            *(f32x4*)&Glds[(((j * 8 + cc) * kM) + b) * 4] = gv;
        }
    }
    __syncthreads();

    // ---- Phase B: this wave's k's; H in registers ----
    D16 acc; acc.v = (f32x16){};
    #pragma unroll 1
    for (int ki = 0; ki < 3; ++ki) {
        const int k = __builtin_amdgcn_readfirstlane(cKset[wv * 3 + ki]);
        f32x2 E2[5];
        compute_E(k, gb, x_cont, x_cat, cont_W1, cont_b1, cont_W2, cont_b2,
                  cat_tables, E2);
        f32x2 g2[16];
        matvec30(E2, sW1 + kD * kL1, g2, 0.0f);           // W1b rows 10..19
        // lane keeps i ranges: kstep0 -> 8*ihalf..+7 ; kstep1 -> 16+8*ihalf..+7
        f32x4 hk0a = {g2[4 * ihalf].x,     g2[4 * ihalf].y,
                      g2[4 * ihalf + 1].x, g2[4 * ihalf + 1].y};
        f32x4 hk0b = {g2[4 * ihalf + 2].x, g2[4 * ihalf + 2].y,
                      g2[4 * ihalf + 3].x, g2[4 * ihalf + 3].y};
        f32x4 hk1a = {g2[8 + 4 * ihalf].x,     g2[8 + 4 * ihalf].y,
                      g2[8 + 4 * ihalf + 1].x, g2[8 + 4 * ihalf + 1].y};
        f32x4 hk1b = {g2[8 + 4 * ihalf + 2].x, g2[8 + 4 * ihalf + 2].y,
                      g2[8 + 4 * ihalf + 3].x, g2[8 + 4 * ihalf + 3].y};

        #pragma unroll 2
        for (int j = 0; j <= k; ++j) {
            const int p = j * kQ - (j * (j - 1)) / 2 + (k - j);
            const float wp = out_w[p];                    // s_load
            const f32x4* bp = (const f32x4*)(pairBias + p * 32);
            const f32x4 zero4 = {0.0f, 0.0f, 0.0f, 0.0f};

            // kstep0: chunks 2*ihalf, 2*ihalf+1 ; kstep1: +4
            const f32x4 g0a = *(const f32x4*)&Glds[(((j * 8 + 2 * ihalf) * kM) + b) * 4];
            const f32x4 g0b = *(const f32x4*)&Glds[(((j * 8 + 2 * ihalf + 1) * kM) + b) * 4];
            const f32x4 g1a = *(const f32x4*)&Glds[(((j * 8 + 4 + 2 * ihalf) * kM) + b) * 4];
            const f32x4 g1b = *(const f32x4*)&Glds[(((j * 8 + 4 + 2 * ihalf + 1) * kM) + b) * 4];
            const f32x4 b0a = bp[2 * ihalf];
            const f32x4 b0b = bp[2 * ihalf + 1];
            const f32x4 b1a = bp[4 + 2 * ihalf];
            const f32x4 b1b = bp[4 + 2 * ihalf + 1];

            const f32x4 t0a = __builtin_elementwise_max(g0a + hk0a + b0a, zero4);
            const f32x4 t0b = __builtin_elementwise_max(g0b + hk0b + b0b, zero4);
            const f32x4 t1a = __builtin_elementwise_max(g1a + hk1a + b1a, zero4);
            const f32x4 t1b = __builtin_elementwise_max(g1b + hk1b + b1b, zero4);

            ABu a0, a1;
            a0.w[0] = pack_trunc(t0a.x, t0a.y);
            a0.w[1] = pack_trunc(t0a.z, t0a.w);
            a0.w[2] = pack_trunc(t0b.x, t0b.y);
            a0.w[3] = pack_trunc(t0b.z, t0b.w);
            a1.w[0] = pack_trunc(t1a.x, t1a.y);
            a1.w[1] = pack_trunc(t1a.z, t1a.w);
            a1.w[2] = pack_trunc(t1b.x, t1b.y);
            a1.w[3] = pack_trunc(t1b.z, t1b.w);

            D16 d; d.v = (f32x16){};
            d.v = __builtin_amdgcn_mfma_f32_32x32x16_bf16(a0.s, bf0.s, d.v, 0, 0, 0);
            d.v = __builtin_amdgcn_mfma_f32_32x32x16_bf16(a1.s, bf1.s, d.v, 0, 0, 0);

            const float ws = wp * w3v6;
            const f32x2 ws2 = {ws, ws};
            const f32x2 zero2 = {0.0f, 0.0f};
            #pragma unroll
            for (int r = 0; r < 8; ++r)
                acc.p[r] = __builtin_elementwise_fma(
                    __builtin_elementwise_max(d.p[r], zero2), ws2, acc.p[r]);
        }
    }

    // ---- reduce over cols n (32-lane halves), then waves via LDS atomics ----
    #pragma unroll
    for (int r = 0; r < 16; ++r) {
        float v = acc.f[r];
        v += __shfl_xor(v, 1, 64);
        v += __shfl_xor(v, 2, 64);
        v += __shfl_xor(v, 4, 64);
        v += __shfl_xor(v, 8, 64);
        v += __shfl_xor(v, 16, 64);
        acc.f[r] = v;
    }
    if (b == 0) {   // lanes 0 and 32 of each wave
        #pragma unroll
        for (int r = 0; r < 16; ++r) {
            const int m = (r & 3) + 8 * (r >> 2) + 4 * ihalf;   // batch row
            atomicAdd(&etab[m], acc.f[r]);
        }
    }
    __syncthreads();

    if (tid < kM) {
        float eta = etab[tid] + pairBias[kNPairs * 32];   // out_b + sb3 term
        eta = fminf(fmaxf(eta, -20.0f), 20.0f);
        const int ob = blockIdx.x * kM + tid;
        out[ob] = __expf(eta) * exposure[ob];
    }
}

extern "C" void kernel_launch(void* const* d_in, const int* in_sizes, int n_in,
                              void* d_out, int out_size, void* d_ws, size_t ws_size,
                              hipStream_t stream) {
    (void)n_in; (void)out_size; (void)ws_size;
    const float* x_cont     = (const float*)d_in[0];
    const int*   x_cat      = (const int*)  d_in[1];
    const float* exposure   = (const float*)d_in[2];
    const float* cont_W1    = (const float*)d_in[3];
    const float* cont_b1    = (const float*)d_in[4];
    const float* cont_W2    = (const float*)d_in[5];
    const float* cont_b2    = (const float*)d_in[6];
    const float* cat_tables = (const float*)d_in[7];
    const float* tokens     = (const float*)d_in[8];
    const float* sW1        = (const float*)d_in[9];
    const float* sb1        = (const float*)d_in[10];
    const float* sW2        = (const float*)d_in[11];
    const float* sb2        = (const float*)d_in[12];
    const float* sW3        = (const float*)d_in[13];
    const float* sb3        = (const float*)d_in[14];
    const float* out_w      = (const float*)d_in[15];
    const float* out_b      = (const float*)d_in[16];

    float* pairBias = (float*)d_ws;   // (78*32+1)*4 B

    {
        const int n = kNPairs * 32 + 1;
        pairbias_kernel<<<(n + 255) / 256, 256, 0, stream>>>(
            tokens, sW1, sb1, sb3, out_w, out_b, pairBias);
    }

    const int B = in_sizes[2];        // exposure is [B]
    pin_main<<<B / kM, kBlock, 0, stream>>>(
        x_cont, x_cat, exposure, cont_W1, cont_b1, cont_W2, cont_b2,
        cat_tables, sW1, sW2, sb2, sW3, out_w, pairBias,
        (float*)d_out);
}

// Round 6
// 167.967 us; speedup vs baseline: 1.6834x; 1.6834x over previous
//
#include <hip/hip_runtime.h>
#include <math.h>

typedef short bf16x8 __attribute__((ext_vector_type(8)));
typedef float f32x16 __attribute__((ext_vector_type(16)));
typedef float f32x4  __attribute__((ext_vector_type(4)));
typedef float f32x2  __attribute__((ext_vector_type(2)));
typedef unsigned int u32x4 __attribute__((ext_vector_type(4)));

namespace {
constexpr int kNCont = 6, kNCat = 6, kNCategories = 100;
constexpr int kQ = 12, kD = 10, kHid = 20, kD0 = 10;
constexpr int kL1 = 30, kL2 = 20, kNPairs = 78;
constexpr int kM = 32;            // batch tile per block
constexpr int kBlock = 256;       // 4 waves
}

// Per-wave k ownership (partition of 0..11); pair counts 19/20/20/19.
__constant__ int cKset[12] = {11, 4, 1, 10, 5, 2, 9, 8, 0, 7, 6, 3};

union ABu { u32x4 u; bf16x8 s; unsigned int w[4]; unsigned short h[8]; };

__device__ __forceinline__ float uf(unsigned int x) { return __uint_as_float(x); }
__device__ __forceinline__ unsigned int fu(float x) { return __float_as_uint(x); }
__device__ __forceinline__ unsigned short f2bf_rne(float v) {
    unsigned int x = fu(v);
    return (unsigned short)((x + 0x7FFFu + ((x >> 16) & 1u)) >> 16);
}
// pack two f32 to bf16x2 by truncation (1 v_perm): lo16=hi(src0), hi16=hi(src1)
__device__ __forceinline__ unsigned int pack_trunc(float e0, float e1) {
    return __builtin_amdgcn_perm(fu(e1), fu(e0), 0x07060302u);
}

// bias[p][i] (i<30) = sb1[i] + tokens[p]@sW1[20:30]; i=30,31 -> 0.
// Slot [78*32]: out_b + sb3/6 * sum(out_w).
__global__ void pairbias_kernel(const float* __restrict__ tokens,
                                const float* __restrict__ sW1,
                                const float* __restrict__ sb1,
                                const float* __restrict__ sb3,
                                const float* __restrict__ out_w,
                                const float* __restrict__ out_b,
                                float* __restrict__ pairBias) {
    const int t = blockIdx.x * blockDim.x + threadIdx.x;
    if (t < kNPairs * 32) {
        const int p = t >> 5, i = t & 31;
        float val = 0.0f;
        if (i < kL1) {
            val = sb1[i];
            #pragma unroll
            for (int d = 0; d < kD0; ++d)
                val = fmaf(tokens[p * kD0 + d], sW1[(2 * kD + d) * kL1 + i], val);
        }
        pairBias[t] = val;
    } else if (t == kNPairs * 32) {
        float s = 0.0f;
        for (int p = 0; p < kNPairs; ++p) s += out_w[p];
        pairBias[t] = out_b[0] + sb3[0] * (1.0f / 6.0f) * s;
    }
}

// Embedding E[gb,q,:] as 5 f32x2. q is SCALAR. All indices static.
__device__ __forceinline__ void compute_E(
    int q, int gb,
    const float* __restrict__ x_cont, const int* __restrict__ x_cat,
    const float* __restrict__ cont_W1, const float* __restrict__ cont_b1,
    const float* __restrict__ cont_W2, const float* __restrict__ cont_b2,
    const float* __restrict__ cat_tables, f32x2 E2[5])
{
    if (q < kNCont) {
        const float x = x_cont[gb * kNCont + q];
        #pragma unroll
        for (int dd = 0; dd < 5; ++dd)
            E2[dd] = f32x2{cont_b2[q * kD + 2 * dd], cont_b2[q * kD + 2 * dd + 1]};
        #pragma unroll
        for (int h = 0; h < kHid; ++h) {
            const float pre = fmaf(x, cont_W1[q * kHid + h], cont_b1[q * kHid + h]);
            const float hv  = fmaxf(pre, 0.0f);
            const f32x2 hv2 = {hv, hv};
            const float* w2 = cont_W2 + (q * kHid + h) * kD;
            #pragma unroll
            for (int dd = 0; dd < 5; ++dd)
                E2[dd] = __builtin_elementwise_fma(
                    hv2, f32x2{w2[2 * dd], w2[2 * dd + 1]}, E2[dd]);
        }
    } else {
        const int c   = q - kNCont;
        const int idx = x_cat[gb * kNCat + c];
        const float* src = cat_tables + (c * kNCategories + idx) * kD;
        #pragma unroll
        for (int dd = 0; dd < 5; ++dd)
            E2[dd] = f32x2{src[2 * dd], src[2 * dd + 1]};
    }
}

// g2[0..14] = E @ W (30 outputs as 15 f32x2); g2[15] = {v30, 0}. W scalar ptr.
// All g2 indices are literal (fully unrolled).
__device__ __forceinline__ void matvec30(const f32x2 E2[5],
                                         const float* __restrict__ W,
                                         f32x2 g2[16], float v30)
{
    #pragma unroll
    for (int ii = 0; ii < 15; ++ii) g2[ii] = f32x2{0.0f, 0.0f};
    #pragma unroll
    for (int d = 0; d < kD; ++d) {
        const float ed = (d & 1) ? E2[d >> 1].y : E2[d >> 1].x;  // d static
        const f32x2 ed2 = {ed, ed};
        const float* wr = W + d * kL1;
        #pragma unroll
        for (int ii = 0; ii < 15; ++ii)
            g2[ii] = __builtin_elementwise_fma(
                ed2, f32x2{wr[2 * ii], wr[2 * ii + 1]}, g2[ii]);
    }
    g2[15] = f32x2{v30, 0.0f};
}

__global__ __launch_bounds__(kBlock, 3) void pin_main(
    const float* __restrict__ x_cont,
    const int*   __restrict__ x_cat,
    const float* __restrict__ exposure,
    const float* __restrict__ cont_W1,
    const float* __restrict__ cont_b1,
    const float* __restrict__ cont_W2,
    const float* __restrict__ cont_b2,
    const float* __restrict__ cat_tables,
    const float* __restrict__ sW1,     // [30,30]
    const float* __restrict__ sW2,     // [30,20]
    const float* __restrict__ sb2,     // [20]
    const float* __restrict__ sW3,     // [20]
    const float* __restrict__ out_w,   // [78]
    const float* __restrict__ pairBias,// [78*32 + 1]
    float* __restrict__ out)
{
    // G f32, A-frag chunk layout: [j][cc=i/4][b][4 f32]; lane-contiguous b128.
    __shared__ float Glds[kQ * 8 * kM * 4];          // 49152 B
    __shared__ float etab[kM];                        // 128 B

    const int tid   = threadIdx.x;
    const int lane  = tid & 63;
    const int b     = lane & 31;          // batch row / MFMA col n
    const int ihalf = lane >> 5;          // fragment k-half selector
    const int wv    = __builtin_amdgcn_readfirstlane((int)(tid >> 6));
    const int gb    = blockIdx.x * kM + b;

    if (tid < kM) etab[tid] = 0.0f;

    // ---- B fragments (sW2 + sb2 ones-row), RNE once ----
    ABu bf0, bf1;
    #pragma unroll
    for (int e = 0; e < 8; ++e) {
        const int k0 = ihalf * 8 + e;
        const int k1 = 16 + ihalf * 8 + e;
        float v0 = 0.0f, v1 = 0.0f;
        if (b < kL2) {
            v0 = (k0 < kL1) ? sW2[k0 * kL2 + b] : (k0 == 30 ? sb2[b] : 0.0f);
            v1 = (k1 < kL1) ? sW2[k1 * kL2 + b] : (k1 == 30 ? sb2[b] : 0.0f);
        }
        bf0.h[e] = f2bf_rne(v0);
        bf1.h[e] = f2bf_rne(v1);
    }
    const float w3v6 = (b < kL2 ? sW3[b] : 0.0f) * (1.0f / 6.0f);

    // ---- Phase A: G[j] = E[j]@W1a (ones row at i=30) -> LDS f32 ----
    #pragma unroll 1
    for (int jj = 0; jj < 3; ++jj) {
        const int j = wv * 3 + jj;                        // scalar
        f32x2 E2[5];
        compute_E(j, gb, x_cont, x_cat, cont_W1, cont_b1, cont_W2, cont_b2,
                  cat_tables, E2);
        f32x2 g2[16];
        matvec30(E2, sW1, g2, 1.0f);                      // W1a rows 0..9
        // STATIC register indices; only the LDS address depends on ihalf.
        if (ihalf == 0) {
            #pragma unroll
            for (int c = 0; c < 4; ++c) {                 // chunks 0..3, i=0..15
                f32x4 gv = {g2[2 * c].x, g2[2 * c].y,
                            g2[2 * c + 1].x, g2[2 * c + 1].y};
                *(f32x4*)&Glds[(((j * 8 + c) * kM) + b) * 4] = gv;
            }
        } else {
            #pragma unroll
            for (int c = 0; c < 4; ++c) {                 // chunks 4..7, i=16..31
                f32x4 gv = {g2[8 + 2 * c].x, g2[8 + 2 * c].y,
                            g2[8 + 2 * c + 1].x, g2[8 + 2 * c + 1].y};
                *(f32x4*)&Glds[(((j * 8 + 4 + c) * kM) + b) * 4] = gv;
            }
        }
    }
    __syncthreads();

    // ---- Phase B: this wave's k's; H in registers (static selection) ----
    f32x16 acc = {};
    #pragma unroll 1
    for (int ki = 0; ki < 3; ++ki) {
        const int k = __builtin_amdgcn_readfirstlane(cKset[wv * 3 + ki]);
        f32x2 E2[5];
        compute_E(k, gb, x_cont, x_cat, cont_W1, cont_b1, cont_W2, cont_b2,
                  cat_tables, E2);
        f32x2 g2[16];
        matvec30(E2, sW1 + kD * kL1, g2, 0.0f);           // W1b rows 10..19
        // Lane keeps i-ranges: kstep0 -> 8*ihalf..+7 ; kstep1 -> 16+8*ihalf..+7
        f32x4 hk0a, hk0b, hk1a, hk1b;
        if (ihalf == 0) {
            hk0a = f32x4{g2[0].x,  g2[0].y,  g2[1].x,  g2[1].y};
            hk0b = f32x4{g2[2].x,  g2[2].y,  g2[3].x,  g2[3].y};
            hk1a = f32x4{g2[8].x,  g2[8].y,  g2[9].x,  g2[9].y};
            hk1b = f32x4{g2[10].x, g2[10].y, g2[11].x, g2[11].y};
        } else {
            hk0a = f32x4{g2[4].x,  g2[4].y,  g2[5].x,  g2[5].y};
            hk0b = f32x4{g2[6].x,  g2[6].y,  g2[7].x,  g2[7].y};
            hk1a = f32x4{g2[12].x, g2[12].y, g2[13].x, g2[13].y};
            hk1b = f32x4{g2[14].x, g2[14].y, g2[15].x, g2[15].y};
        }

        #pragma unroll 2
        for (int j = 0; j <= k; ++j) {
            const int p = j * kQ - (j * (j - 1)) / 2 + (k - j);
            const float wp = out_w[p];                    // s_load
            const float* bp = pairBias + p * 32;
            const f32x4 zero4 = {0.0f, 0.0f, 0.0f, 0.0f};

            // LDS/global addresses may be dynamic; register values static.
            const f32x4 g0a = *(const f32x4*)&Glds[(((j * 8 + 2 * ihalf) * kM) + b) * 4];
            const f32x4 g0b = *(const f32x4*)&Glds[(((j * 8 + 2 * ihalf + 1) * kM) + b) * 4];
            const f32x4 g1a = *(const f32x4*)&Glds[(((j * 8 + 4 + 2 * ihalf) * kM) + b) * 4];
            const f32x4 g1b = *(const f32x4*)&Glds[(((j * 8 + 4 + 2 * ihalf + 1) * kM) + b) * 4];
            const f32x4 b0a = *(const f32x4*)(bp + 8 * ihalf);
            const f32x4 b0b = *(const f32x4*)(bp + 8 * ihalf + 4);
            const f32x4 b1a = *(const f32x4*)(bp + 16 + 8 * ihalf);
            const f32x4 b1b = *(const f32x4*)(bp + 16 + 8 * ihalf + 4);

            const f32x4 t0a = __builtin_elementwise_max(g0a + hk0a + b0a, zero4);
            const f32x4 t0b = __builtin_elementwise_max(g0b + hk0b + b0b, zero4);
            const f32x4 t1a = __builtin_elementwise_max(g1a + hk1a + b1a, zero4);
            const f32x4 t1b = __builtin_elementwise_max(g1b + hk1b + b1b, zero4);

            ABu a0, a1;
            a0.w[0] = pack_trunc(t0a.x, t0a.y);
            a0.w[1] = pack_trunc(t0a.z, t0a.w);
            a0.w[2] = pack_trunc(t0b.x, t0b.y);
            a0.w[3] = pack_trunc(t0b.z, t0b.w);
            a1.w[0] = pack_trunc(t1a.x, t1a.y);
            a1.w[1] = pack_trunc(t1a.z, t1a.w);
            a1.w[2] = pack_trunc(t1b.x, t1b.y);
            a1.w[3] = pack_trunc(t1b.z, t1b.w);

            f32x16 d = {};
            d = __builtin_amdgcn_mfma_f32_32x32x16_bf16(a0.s, bf0.s, d, 0, 0, 0);
            d = __builtin_amdgcn_mfma_f32_32x32x16_bf16(a1.s, bf1.s, d, 0, 0, 0);

            const float ws = wp * w3v6;
            const f32x16 zero16 = {};
            const f32x16 relu = __builtin_elementwise_max(d, zero16);
            acc += relu * ws;   // scalar splat; contracts to v_pk_fma_f32
        }
    }

    // ---- reduce over cols n (32-lane halves), then waves via LDS atomics ----
    float accf[16];
    #pragma unroll
    for (int r = 0; r < 16; ++r) {
        float v = acc[r];                 // r literal
        v += __shfl_xor(v, 1, 64);
        v += __shfl_xor(v, 2, 64);
        v += __shfl_xor(v, 4, 64);
        v += __shfl_xor(v, 8, 64);
        v += __shfl_xor(v, 16, 64);
        accf[r] = v;
    }
    if (b == 0) {   // lanes 0 and 32 of each wave
        #pragma unroll
        for (int r = 0; r < 16; ++r) {
            const int m = (r & 3) + 8 * (r >> 2) + 4 * ihalf;   // batch row
            atomicAdd(&etab[m], accf[r]);
        }
    }
    __syncthreads();

    if (tid < kM) {
        float eta = etab[tid] + pairBias[kNPairs * 32];   // out_b + sb3 term
        eta = fminf(fmaxf(eta, -20.0f), 20.0f);
        const int ob = blockIdx.x * kM + tid;
        out[ob] = __expf(eta) * exposure[ob];
    }
}

extern "C" void kernel_launch(void* const* d_in, const int* in_sizes, int n_in,
                              void* d_out, int out_size, void* d_ws, size_t ws_size,
                              hipStream_t stream) {
    (void)n_in; (void)out_size; (void)ws_size;
    const float* x_cont     = (const float*)d_in[0];
    const int*   x_cat      = (const int*)  d_in[1];
    const float* exposure   = (const float*)d_in[2];
    const float* cont_W1    = (const float*)d_in[3];
    const float* cont_b1    = (const float*)d_in[4];
    const float* cont_W2    = (const float*)d_in[5];
    const float* cont_b2    = (const float*)d_in[6];
    const float* cat_tables = (const float*)d_in[7];
    const float* tokens     = (const float*)d_in[8];
    const float* sW1        = (const float*)d_in[9];
    const float* sb1        = (const float*)d_in[10];
    const float* sW2        = (const float*)d_in[11];
    const float* sb2        = (const float*)d_in[12];
    const float* sW3        = (const float*)d_in[13];
    const float* sb3        = (const float*)d_in[14];
    const float* out_w      = (const float*)d_in[15];
    const float* out_b      = (const float*)d_in[16];

    float* pairBias = (float*)d_ws;   // (78*32+1)*4 B

    {
        const int n = kNPairs * 32 + 1;
        pairbias_kernel<<<(n + 255) / 256, 256, 0, stream>>>(
            tokens, sW1, sb1, sb3, out_w, out_b, pairBias);
    }

    const int B = in_sizes[2];        // exposure is [B]
    pin_main<<<B / kM, kBlock, 0, stream>>>(
        x_cont, x_cat, exposure, cont_W1, cont_b1, cont_W2, cont_b2,
        cat_tables, sW1, sW2, sb2, sW3, out_w, pairBias,
        (float*)d_out);
}

// Round 7
// 153.176 us; speedup vs baseline: 1.8459x; 1.0966x over previous
//
#include <hip/hip_runtime.h>
#include <math.h>

typedef short bf16x8 __attribute__((ext_vector_type(8)));
typedef float f32x16 __attribute__((ext_vector_type(16)));
typedef float f32x4  __attribute__((ext_vector_type(4)));
typedef float f32x2  __attribute__((ext_vector_type(2)));
typedef unsigned int u32x4 __attribute__((ext_vector_type(4)));

namespace {
constexpr int kNCont = 6, kNCat = 6, kNCategories = 100;
constexpr int kQ = 12, kD = 10, kHid = 20, kD0 = 10;
constexpr int kL1 = 30, kL2 = 20, kNPairs = 78;
constexpr int kM = 32;            // batch tile per block
constexpr int kBlock = 256;       // 4 waves
}

// Per-wave k ownership (partition of 0..11); pair counts 19/20/20/19.
__constant__ int cKset[12] = {11, 4, 1, 10, 5, 2, 9, 8, 0, 7, 6, 3};

union ABu { u32x4 u; bf16x8 s; unsigned int w[4]; unsigned short h[8]; };
union D16 { f32x16 v; f32x4 q[4]; };

__device__ __forceinline__ float uf(unsigned int x) { return __uint_as_float(x); }
__device__ __forceinline__ unsigned int fu(float x) { return __float_as_uint(x); }
__device__ __forceinline__ unsigned short f2bf_rne(float v) {
    unsigned int x = fu(v);
    return (unsigned short)((x + 0x7FFFu + ((x >> 16) & 1u)) >> 16);
}
// pack two f32 to bf16x2 by truncation (1 v_perm): low16=hi(e0), hi16=hi(e1)
__device__ __forceinline__ unsigned int pack_trunc(float e0, float e1) {
    return __builtin_amdgcn_perm(fu(e1), fu(e0), 0x07060302u);
}

// bias[p][i] (i<30) = sb1[i] + tokens[p]@sW1[20:30]; i=30,31 -> 0.
// Slot [78*32]: out_b + sb3/6 * sum(out_w).
__global__ void pairbias_kernel(const float* __restrict__ tokens,
                                const float* __restrict__ sW1,
                                const float* __restrict__ sb1,
                                const float* __restrict__ sb3,
                                const float* __restrict__ out_w,
                                const float* __restrict__ out_b,
                                float* __restrict__ pairBias) {
    const int t = blockIdx.x * blockDim.x + threadIdx.x;
    if (t < kNPairs * 32) {
        const int p = t >> 5, i = t & 31;
        float val = 0.0f;
        if (i < kL1) {
            val = sb1[i];
            #pragma unroll
            for (int d = 0; d < kD0; ++d)
                val = fmaf(tokens[p * kD0 + d], sW1[(2 * kD + d) * kL1 + i], val);
        }
        pairBias[t] = val;
    } else if (t == kNPairs * 32) {
        float s = 0.0f;
        for (int p = 0; p < kNPairs; ++p) s += out_w[p];
        pairBias[t] = out_b[0] + sb3[0] * (1.0f / 6.0f) * s;
    }
}

// Embedding E[gb,q,:] as 5 f32x2. q is SCALAR. All register indices static.
__device__ __forceinline__ void compute_E(
    int q, int gb,
    const float* __restrict__ x_cont, const int* __restrict__ x_cat,
    const float* __restrict__ cont_W1, const float* __restrict__ cont_b1,
    const float* __restrict__ cont_W2, const float* __restrict__ cont_b2,
    const float* __restrict__ cat_tables, f32x2 E2[5])
{
    if (q < kNCont) {
        const float x = x_cont[gb * kNCont + q];
        #pragma unroll
        for (int dd = 0; dd < 5; ++dd)
            E2[dd] = f32x2{cont_b2[q * kD + 2 * dd], cont_b2[q * kD + 2 * dd + 1]};
        #pragma unroll
        for (int h = 0; h < kHid; ++h) {
            const float pre = fmaf(x, cont_W1[q * kHid + h], cont_b1[q * kHid + h]);
            const float hv  = fmaxf(pre, 0.0f);
            const f32x2 hv2 = {hv, hv};
            const float* w2 = cont_W2 + (q * kHid + h) * kD;
            #pragma unroll
            for (int dd = 0; dd < 5; ++dd)
                E2[dd] = __builtin_elementwise_fma(
                    hv2, f32x2{w2[2 * dd], w2[2 * dd + 1]}, E2[dd]);
        }
    } else {
        const int c   = q - kNCont;
        const int idx = x_cat[gb * kNCat + c];
        const float* src = cat_tables + (c * kNCategories + idx) * kD;
        #pragma unroll
        for (int dd = 0; dd < 5; ++dd)
            E2[dd] = f32x2{src[2 * dd], src[2 * dd + 1]};
    }
}

// Build the E B-operand fragment: B[k=d][n=b], element e <-> d = 8*ihalf+e.
// d=10 carries 1.0 (ones-row injector); d>=11 zero.
__device__ __forceinline__ ABu build_efrag(const f32x2 E2[5], int ihalf) {
    ABu ef;
    if (ihalf == 0) {
        ef.w[0] = pack_trunc(E2[0].x, E2[0].y);   // d0,1
        ef.w[1] = pack_trunc(E2[1].x, E2[1].y);   // d2,3
        ef.w[2] = pack_trunc(E2[2].x, E2[2].y);   // d4,5
        ef.w[3] = pack_trunc(E2[3].x, E2[3].y);   // d6,7
    } else {
        ef.w[0] = pack_trunc(E2[4].x, E2[4].y);   // d8,9
        ef.w[1] = 0x00003F80u;                    // d10=1.0, d11=0
        ef.w[2] = 0u;
        ef.w[3] = 0u;
    }
    return ef;
}

__global__ __launch_bounds__(kBlock, 3) void pin_main(
    const float* __restrict__ x_cont,
    const int*   __restrict__ x_cat,
    const float* __restrict__ exposure,
    const float* __restrict__ cont_W1,
    const float* __restrict__ cont_b1,
    const float* __restrict__ cont_W2,
    const float* __restrict__ cont_b2,
    const float* __restrict__ cat_tables,
    const float* __restrict__ sW1,     // [30,30]
    const float* __restrict__ sW2,     // [30,20]
    const float* __restrict__ sb2,     // [20]
    const float* __restrict__ sW3,     // [20]
    const float* __restrict__ out_w,   // [78]
    const float* __restrict__ pairBias,// [78*32 + 1]
    float* __restrict__ out)
{
    // G f32: [j][cc=i/4][b][4 f32]; lane-contiguous b128 (round-6-verified).
    __shared__ float Glds[kQ * 8 * kM * 4];          // 49152 B
    __shared__ float etab[kM];                        // 128 B

    const int tid   = threadIdx.x;
    const int lane  = tid & 63;
    const int b     = lane & 31;          // batch row (D col) / frag m-or-n
    const int ihalf = lane >> 5;          // fragment k-half selector
    const int wv    = __builtin_amdgcn_readfirstlane((int)(tid >> 6));
    const int gb    = blockIdx.x * kM + b;

    if (tid < kM) etab[tid] = 0.0f;

    // tau: C-row m holds W1-column tau(m), so C-regs land in B-frag order.
    // tau(m) = m + {0,+4,-4,0} by (m>>2)&3.
    const int q2  = (b >> 2) & 3;
    const int tau = b + (q2 == 1 ? 4 : (q2 == 2 ? -4 : 0));

    // ---- W1a/W1b A-operand fragments: A[m][k=d] = sW1[d][tau(m)] ----
    ABu wa, wb;
    wa.u = u32x4{0, 0, 0, 0};
    wb.u = u32x4{0, 0, 0, 0};
    if (ihalf == 0) {
        #pragma unroll
        for (int e = 0; e < 8; ++e) {                 // d = e (0..7)
            const float va = (tau < kL1) ? sW1[e * kL1 + tau] : 0.0f;
            const float vb = (tau < kL1) ? sW1[(kD + e) * kL1 + tau] : 0.0f;
            wa.h[e] = f2bf_rne(va);
            wb.h[e] = f2bf_rne(vb);
        }
    } else {
        #pragma unroll
        for (int e = 0; e < 2; ++e) {                 // d = 8+e
            const float va = (tau < kL1) ? sW1[(8 + e) * kL1 + tau] : 0.0f;
            const float vb = (tau < kL1) ? sW1[(18 + e) * kL1 + tau] : 0.0f;
            wa.h[e] = f2bf_rne(va);
            wb.h[e] = f2bf_rne(vb);
        }
        wa.h[2] = (tau == 30) ? (unsigned short)0x3F80 : (unsigned short)0;  // ones row
        // wb.h[2] stays 0 (H has no ones row); e>=3 zero.
    }

    // ---- sW2 A-operand frags (rows o = b; k = i), + sb2 ones-row ----
    ABu bf0, bf1;
    #pragma unroll
    for (int e = 0; e < 8; ++e) {
        const int k0 = ihalf * 8 + e;
        const int k1 = 16 + ihalf * 8 + e;
        float v0 = 0.0f, v1 = 0.0f;
        if (b < kL2) {
            v0 = (k0 < kL1) ? sW2[k0 * kL2 + b] : (k0 == 30 ? sb2[b] : 0.0f);
            v1 = (k1 < kL1) ? sW2[k1 * kL2 + b] : (k1 == 30 ? sb2[b] : 0.0f);
        }
        bf0.h[e] = f2bf_rne(v0);
        bf1.h[e] = f2bf_rne(v1);
    }

    // ---- Phase A: G[j] via one MFMA each, store C-regs to LDS ----
    #pragma unroll 1
    for (int jj = 0; jj < 3; ++jj) {
        const int j = wv * 3 + jj;                    // scalar
        f32x2 E2[5];
        compute_E(j, gb, x_cont, x_cat, cont_W1, cont_b1, cont_W2, cont_b2,
                  cat_tables, E2);
        const ABu ef = build_efrag(E2, ihalf);
        f32x16 dG = {};
        dG = __builtin_amdgcn_mfma_f32_32x32x16_bf16(wa.s, ef.s, dG, 0, 0, 0);
        D16 u; u.v = dG;
        if (ihalf == 0) {   // regs hold i = 0..7, 16..23 -> chunks 0,1,4,5
            *(f32x4*)&Glds[((j * 8 + 0) * kM + b) * 4] = u.q[0];
            *(f32x4*)&Glds[((j * 8 + 1) * kM + b) * 4] = u.q[1];
            *(f32x4*)&Glds[((j * 8 + 4) * kM + b) * 4] = u.q[2];
            *(f32x4*)&Glds[((j * 8 + 5) * kM + b) * 4] = u.q[3];
        } else {            // i = 8..15, 24..31 -> chunks 2,3,6,7
            *(f32x4*)&Glds[((j * 8 + 2) * kM + b) * 4] = u.q[0];
            *(f32x4*)&Glds[((j * 8 + 3) * kM + b) * 4] = u.q[1];
            *(f32x4*)&Glds[((j * 8 + 6) * kM + b) * 4] = u.q[2];
            *(f32x4*)&Glds[((j * 8 + 7) * kM + b) * 4] = u.q[3];
        }
    }
    __syncthreads();

    // ---- Phase B: wave's k's; H via MFMA, stays in C-regs (frag order) ----
    f32x16 acc = {};
    #pragma unroll 1
    for (int ki = 0; ki < 3; ++ki) {
        const int k = __builtin_amdgcn_readfirstlane(cKset[wv * 3 + ki]);
        f32x2 E2[5];
        compute_E(k, gb, x_cont, x_cat, cont_W1, cont_b1, cont_W2, cont_b2,
                  cat_tables, E2);
        const ABu ef = build_efrag(E2, ihalf);
        f32x16 dH = {};
        dH = __builtin_amdgcn_mfma_f32_32x32x16_bf16(wb.s, ef.s, dH, 0, 0, 0);
        D16 H; H.v = dH;   // q[0],q[1] = kstep0 e0..7; q[2],q[3] = kstep1 e0..7

        #pragma unroll 2
        for (int j = 0; j <= k; ++j) {
            const int p = j * kQ - (j * (j - 1)) / 2 + (k - j);
            const float wp = out_w[p];                // s_load
            const float* bp = pairBias + p * 32;
            const f32x4 zero4 = {0.0f, 0.0f, 0.0f, 0.0f};

            const f32x4 g0a = *(const f32x4*)&Glds[((j * 8 + 2 * ihalf) * kM + b) * 4];
            const f32x4 g0b = *(const f32x4*)&Glds[((j * 8 + 2 * ihalf + 1) * kM + b) * 4];
            const f32x4 g1a = *(const f32x4*)&Glds[((j * 8 + 4 + 2 * ihalf) * kM + b) * 4];
            const f32x4 g1b = *(const f32x4*)&Glds[((j * 8 + 4 + 2 * ihalf + 1) * kM + b) * 4];
            const f32x4 b0a = *(const f32x4*)(bp + 8 * ihalf);
            const f32x4 b0b = *(const f32x4*)(bp + 8 * ihalf + 4);
            const f32x4 b1a = *(const f32x4*)(bp + 16 + 8 * ihalf);
            const f32x4 b1b = *(const f32x4*)(bp + 16 + 8 * ihalf + 4);

            const f32x4 t0a = __builtin_elementwise_max(g0a + H.q[0] + b0a, zero4);
            const f32x4 t0b = __builtin_elementwise_max(g0b + H.q[1] + b0b, zero4);
            const f32x4 t1a = __builtin_elementwise_max(g1a + H.q[2] + b1a, zero4);
            const f32x4 t1b = __builtin_elementwise_max(g1b + H.q[3] + b1b, zero4);

            ABu hf0, hf1;                              // h1 as B-operand
            hf0.w[0] = pack_trunc(t0a.x, t0a.y);
            hf0.w[1] = pack_trunc(t0a.z, t0a.w);
            hf0.w[2] = pack_trunc(t0b.x, t0b.y);
            hf0.w[3] = pack_trunc(t0b.z, t0b.w);
            hf1.w[0] = pack_trunc(t1a.x, t1a.y);
            hf1.w[1] = pack_trunc(t1a.z, t1a.w);
            hf1.w[2] = pack_trunc(t1b.x, t1b.y);
            hf1.w[3] = pack_trunc(t1b.z, t1b.w);

            // D[m=o][n=b]: batch in lanes, outputs in regs
            f32x16 d = {};
            d = __builtin_amdgcn_mfma_f32_32x32x16_bf16(bf0.s, hf0.s, d, 0, 0, 0);
            d = __builtin_amdgcn_mfma_f32_32x32x16_bf16(bf1.s, hf1.s, d, 0, 0, 0);

            const f32x16 zero16 = {};
            const f32x16 relu = __builtin_elementwise_max(d, zero16);
            acc += relu * wp;
        }
    }

    // ---- epilogue: eta[b] = (1/6) * sum_r sW3[o_r] * acc[r] ----
    // o_r = (r&3) + 8*(r>>2) + 4*ihalf; contributions only for o_r < 20.
    float etaL = 0.0f;
    if (ihalf == 0) {       // r=0..11 -> o = 0..3, 8..11, 16..19
        #pragma unroll
        for (int r = 0; r < 12; ++r)
            etaL = fmaf(acc[r], sW3[(r & 3) + 8 * (r >> 2)], etaL);
    } else {                // r=0..7 -> o = 4..7, 12..15
        #pragma unroll
        for (int r = 0; r < 8; ++r)
            etaL = fmaf(acc[r], sW3[(r & 3) + 8 * (r >> 2) + 4], etaL);
    }
    etaL += __shfl_xor(etaL, 32, 64);   // combine o-halves (lane b <-> b+32)
    if (ihalf == 0) atomicAdd(&etab[b], etaL);
    __syncthreads();

    if (tid < kM) {
        float eta = etab[tid] * (1.0f / 6.0f) + pairBias[kNPairs * 32];
        eta = fminf(fmaxf(eta, -20.0f), 20.0f);
        const int ob = blockIdx.x * kM + tid;
        out[ob] = __expf(eta) * exposure[ob];
    }
}

extern "C" void kernel_launch(void* const* d_in, const int* in_sizes, int n_in,
                              void* d_out, int out_size, void* d_ws, size_t ws_size,
                              hipStream_t stream) {
    (void)n_in; (void)out_size; (void)ws_size;
    const float* x_cont     = (const float*)d_in[0];
    const int*   x_cat      = (const int*)  d_in[1];
    const float* exposure   = (const float*)d_in[2];
    const float* cont_W1    = (const float*)d_in[3];
    const float* cont_b1    = (const float*)d_in[4];
    const float* cont_W2    = (const float*)d_in[5];
    const float* cont_b2    = (const float*)d_in[6];
    const float* cat_tables = (const float*)d_in[7];
    const float* tokens     = (const float*)d_in[8];
    const float* sW1        = (const float*)d_in[9];
    const float* sb1        = (const float*)d_in[10];
    const float* sW2        = (const float*)d_in[11];
    const float* sb2        = (const float*)d_in[12];
    const float* sW3        = (const float*)d_in[13];
    const float* sb3        = (const float*)d_in[14];
    const float* out_w      = (const float*)d_in[15];
    const float* out_b      = (const float*)d_in[16];

    float* pairBias = (float*)d_ws;   // (78*32+1)*4 B

    {
        const int n = kNPairs * 32 + 1;
        pairbias_kernel<<<(n + 255) / 256, 256, 0, stream>>>(
            tokens, sW1, sb1, sb3, out_w, out_b, pairBias);
    }

    const int B = in_sizes[2];        // exposure is [B]
    pin_main<<<B / kM, kBlock, 0, stream>>>(
        x_cont, x_cat, exposure, cont_W1, cont_b1, cont_W2, cont_b2,
        cat_tables, sW1, sW2, sb2, sW3, out_w, pairBias,
        (float*)d_out);
}

// Round 8
// 138.550 us; speedup vs baseline: 2.0408x; 1.1056x over previous
//
#include <hip/hip_runtime.h>
#include <math.h>

typedef short bf16x8 __attribute__((ext_vector_type(8)));
typedef float f32x16 __attribute__((ext_vector_type(16)));
typedef float f32x4  __attribute__((ext_vector_type(4)));
typedef float f32x2  __attribute__((ext_vector_type(2)));
typedef unsigned int u32x4 __attribute__((ext_vector_type(4)));
typedef unsigned int u32x2 __attribute__((ext_vector_type(2)));

namespace {
constexpr int kNCont = 6, kNCat = 6, kNCategories = 100;
constexpr int kQ = 12, kD = 10, kHid = 20, kD0 = 10;
constexpr int kL1 = 30, kL2 = 20, kNPairs = 78;
constexpr int kM = 32;            // batch tile per block
constexpr int kBlock = 256;       // 4 waves
constexpr int kES = 6;            // u32 stride per [q][b] E slot (5 used + pad)
}

// Per-wave k ownership (partition of 0..11); pair counts 19/20/20/19.
__constant__ int cKset[12] = {11, 4, 1, 10, 5, 2, 9, 8, 0, 7, 6, 3};

union ABu { u32x4 u; bf16x8 s; unsigned int w[4]; unsigned short h[8]; };
union D16 { f32x16 v; f32x4 q[4]; float f[16]; };

__device__ __forceinline__ unsigned int fu(float x) { return __float_as_uint(x); }
__device__ __forceinline__ unsigned short f2bf_rne(float v) {
    unsigned int x = fu(v);
    return (unsigned short)((x + 0x7FFFu + ((x >> 16) & 1u)) >> 16);
}
// pack two f32 to bf16x2 by truncation: low16 = hi(e0), high16 = hi(e1)
__device__ __forceinline__ unsigned int pack_trunc(float e0, float e1) {
    return __builtin_amdgcn_perm(fu(e1), fu(e0), 0x07060302u);
}

// biasC[p][idx]: bias for pair p pre-permuted into MFMA C-layout.
// idx = reg + 16*ihalf; m = (reg&3)+8*(reg>>2)+4*ihalf; value = biasarr[tau(m)]
// where biasarr[i<30] = sb1[i] + tokens[p]@sW1[20:30], biasarr[30]=1 (sb2 ones
// row injector for layer 2), biasarr[31]=0.  Slot [78*32]: out_b + sb3/6*sum(out_w).
__global__ void pairbias_kernel(const float* __restrict__ tokens,
                                const float* __restrict__ sW1,
                                const float* __restrict__ sb1,
                                const float* __restrict__ sb3,
                                const float* __restrict__ out_w,
                                const float* __restrict__ out_b,
                                float* __restrict__ biasC) {
    const int t = blockIdx.x * blockDim.x + threadIdx.x;
    if (t < kNPairs * 32) {
        const int p = t >> 5, idx = t & 31;
        const int r = idx & 15, ih = idx >> 4;
        const int m = (r & 3) + 8 * (r >> 2) + 4 * ih;
        const int q2 = (m >> 2) & 3;
        const int tau = m + (q2 == 1 ? 4 : (q2 == 2 ? -4 : 0));
        float val;
        if (tau < kL1) {
            val = sb1[tau];
            #pragma unroll
            for (int d = 0; d < kD0; ++d)
                val = fmaf(tokens[p * kD0 + d], sW1[(2 * kD + d) * kL1 + tau], val);
        } else {
            val = (tau == 30) ? 1.0f : 0.0f;
        }
        biasC[t] = val;
    } else if (t == kNPairs * 32) {
        float s = 0.0f;
        for (int p = 0; p < kNPairs; ++p) s += out_w[p];
        biasC[t] = out_b[0] + sb3[0] * (1.0f / 6.0f) * s;
    }
}

// Embedding E[gb,q,:] as 5 f32x2. q is SCALAR. All register indices static.
__device__ __forceinline__ void compute_E(
    int q, int gb,
    const float* __restrict__ x_cont, const int* __restrict__ x_cat,
    const float* __restrict__ cont_W1, const float* __restrict__ cont_b1,
    const float* __restrict__ cont_W2, const float* __restrict__ cont_b2,
    const float* __restrict__ cat_tables, f32x2 E2[5])
{
    if (q < kNCont) {
        const float x = x_cont[gb * kNCont + q];
        #pragma unroll
        for (int dd = 0; dd < 5; ++dd)
            E2[dd] = f32x2{cont_b2[q * kD + 2 * dd], cont_b2[q * kD + 2 * dd + 1]};
        #pragma unroll
        for (int h = 0; h < kHid; ++h) {
            const float pre = fmaf(x, cont_W1[q * kHid + h], cont_b1[q * kHid + h]);
            const float hv  = fmaxf(pre, 0.0f);
            const f32x2 hv2 = {hv, hv};
            const float* w2 = cont_W2 + (q * kHid + h) * kD;
            #pragma unroll
            for (int dd = 0; dd < 5; ++dd)
                E2[dd] = __builtin_elementwise_fma(
                    hv2, f32x2{w2[2 * dd], w2[2 * dd + 1]}, E2[dd]);
        }
    } else {
        const int c   = q - kNCont;
        const int idx = x_cat[gb * kNCat + c];
        const float* src = cat_tables + (c * kNCategories + idx) * kD;
        #pragma unroll
        for (int dd = 0; dd < 5; ++dd)
            E2[dd] = f32x2{src[2 * dd], src[2 * dd + 1]};
    }
}

__global__ __launch_bounds__(kBlock, 4) void pin_main(
    const float* __restrict__ x_cont,
    const int*   __restrict__ x_cat,
    const float* __restrict__ exposure,
    const float* __restrict__ cont_W1,
    const float* __restrict__ cont_b1,
    const float* __restrict__ cont_W2,
    const float* __restrict__ cont_b2,
    const float* __restrict__ cat_tables,
    const float* __restrict__ sW1,     // [30,30]
    const float* __restrict__ sW2,     // [30,20]
    const float* __restrict__ sb2,     // [20]
    const float* __restrict__ sW3,     // [20]
    const float* __restrict__ out_w,   // [78]
    const float* __restrict__ biasC,   // [78*32 + 1], C-layout
    float* __restrict__ out)
{
    // Packed-bf16 E table: [q][b][kES u32] (5 used). 12*32*6*4 = 9216 B.
    __shared__ unsigned int Elds[kQ * kM * kES];
    __shared__ float etab[kM];

    const int tid   = threadIdx.x;
    const int lane  = tid & 63;
    const int b     = lane & 31;          // batch row / MFMA col n
    const int ihalf = lane >> 5;          // fragment k-half selector
    const int wv    = __builtin_amdgcn_readfirstlane((int)(tid >> 6));
    const int gb    = blockIdx.x * kM + b;

    if (tid < kM) etab[tid] = 0.0f;

    // tau: verified round 7 — C-reg order <-> i order for B-frag consumption.
    const int q2  = (b >> 2) & 3;
    const int tau = b + (q2 == 1 ? 4 : (q2 == 2 ? -4 : 0));

    // ---- stacked [W1a;W1b] A-frags: A[m][s] = sW1[s][tau(m)], s<20 ----
    ABu wab0, wab1;
    wab0.u = u32x4{0, 0, 0, 0};
    wab1.u = u32x4{0, 0, 0, 0};
    #pragma unroll
    for (int e = 0; e < 8; ++e) {         // kstep0: s = 8*ihalf + e (0..15)
        const int s = 8 * ihalf + e;
        wab0.h[e] = f2bf_rne((tau < kL1) ? sW1[s * kL1 + tau] : 0.0f);
    }
    if (ihalf == 0) {                      // kstep1: s = 16..19 live, rest 0
        #pragma unroll
        for (int e = 0; e < 4; ++e)
            wab1.h[e] = f2bf_rne((tau < kL1) ? sW1[(16 + e) * kL1 + tau] : 0.0f);
    }

    // ---- layer-2 A-frags (sW2 rows o=b, k-slots i; i=30 -> sb2) — r7 verbatim ----
    ABu bf0, bf1;
    #pragma unroll
    for (int e = 0; e < 8; ++e) {
        const int k0 = ihalf * 8 + e;
        const int k1 = 16 + ihalf * 8 + e;
        float v0 = 0.0f, v1 = 0.0f;
        if (b < kL2) {
            v0 = (k0 < kL1) ? sW2[k0 * kL2 + b] : (k0 == 30 ? sb2[b] : 0.0f);
            v1 = (k1 < kL1) ? sW2[k1 * kL2 + b] : (k1 == 30 ? sb2[b] : 0.0f);
        }
        bf0.h[e] = f2bf_rne(v0);
        bf1.h[e] = f2bf_rne(v1);
    }

    // ---- Phase A: wave computes E for its 3 q's, shares packed bf16 via LDS ----
    #pragma unroll 1
    for (int jj = 0; jj < 3; ++jj) {
        const int q = wv * 3 + jj;                    // scalar
        f32x2 E2[5];
        compute_E(q, gb, x_cont, x_cat, cont_W1, cont_b1, cont_W2, cont_b2,
                  cat_tables, E2);
        const unsigned int ep0 = pack_trunc(E2[0].x, E2[0].y);
        const unsigned int ep1 = pack_trunc(E2[1].x, E2[1].y);
        const unsigned int ep2 = pack_trunc(E2[2].x, E2[2].y);
        const unsigned int ep3 = pack_trunc(E2[3].x, E2[3].y);
        const unsigned int ep4 = pack_trunc(E2[4].x, E2[4].y);
        if (ihalf == 0) {                             // halves redundant; one writes
            unsigned int* dst = &Elds[(q * kM + b) * kES];
            *(u32x2*)(dst)     = u32x2{ep0, ep1};
            *(u32x2*)(dst + 2) = u32x2{ep2, ep3};
            dst[4] = ep4;
        }
    }
    __syncthreads();

    // ---- Phase B: pairs. h1 = [W1a;W1b]@[Ej;Ek] + biasC in ONE MFMA chain ----
    f32x16 acc = {};
    const unsigned int* ebase = &Elds[b * kES];
    #pragma unroll 1
    for (int ki = 0; ki < 3; ++ki) {
        const int k = __builtin_amdgcn_readfirstlane(cKset[wv * 3 + ki]);
        const unsigned int* ekp = ebase + k * kM * kES;
        const u32x2 ek01 = *(const u32x2*)ekp;        // Ek pairs (d01),(d23)
        const u32x2 ek23 = *(const u32x2*)(ekp + 2);  // (d45),(d67)
        const unsigned int ek4 = ekp[4];              // (d89)

        // e1 (kstep1 B-frag) is constant per k: slots 16..19 = Ek d6..9
        ABu e1;
        if (ihalf == 0) e1.u = u32x4{ek23.y, ek4, 0u, 0u};
        else            e1.u = u32x4{0u, 0u, 0u, 0u};

        #pragma unroll 1
        for (int j = 0; j <= k; ++j) {
            const int p = j * kQ - (j * (j - 1)) / 2 + (k - j);
            const unsigned int* ejp = ebase + j * kM * kES;
            const u32x2 ej01 = *(const u32x2*)ejp;
            const u32x2 ej23 = *(const u32x2*)(ejp + 2);
            const unsigned int ej4 = ejp[4];

            // bias in C-layout: 4 broadcast dwordx4 (L1-resident 10 KB table)
            const float* bc = biasC + p * 32 + ihalf * 16;
            D16 cb;
            cb.q[0] = *(const f32x4*)bc;
            cb.q[1] = *(const f32x4*)(bc + 4);
            cb.q[2] = *(const f32x4*)(bc + 8);
            cb.q[3] = *(const f32x4*)(bc + 12);

            // B-frag kstep0: slots 0..9 = Ej d0..9, slots 10..15 = Ek d0..5
            ABu e0;
            if (ihalf == 0) e0.u = u32x4{ej01.x, ej01.y, ej23.x, ej23.y};
            else            e0.u = u32x4{ej4, ek01.x, ek01.y, ek23.x};

            f32x16 d1 = __builtin_amdgcn_mfma_f32_32x32x16_bf16(wab0.s, e0.s, cb.v, 0, 0, 0);
            d1 = __builtin_amdgcn_mfma_f32_32x32x16_bf16(wab1.s, e1.s, d1, 0, 0, 0);

            D16 t; t.v = __builtin_elementwise_max(d1, (f32x16){});
            ABu hf0, hf1;                              // h1 as layer-2 B-operand
            hf0.w[0] = pack_trunc(t.q[0].x, t.q[0].y);
            hf0.w[1] = pack_trunc(t.q[0].z, t.q[0].w);
            hf0.w[2] = pack_trunc(t.q[1].x, t.q[1].y);
            hf0.w[3] = pack_trunc(t.q[1].z, t.q[1].w);
            hf1.w[0] = pack_trunc(t.q[2].x, t.q[2].y);
            hf1.w[1] = pack_trunc(t.q[2].z, t.q[2].w);
            hf1.w[2] = pack_trunc(t.q[3].x, t.q[3].y);
            hf1.w[3] = pack_trunc(t.q[3].z, t.q[3].w);

            f32x16 d2 = {};
            d2 = __builtin_amdgcn_mfma_f32_32x32x16_bf16(bf0.s, hf0.s, d2, 0, 0, 0);
            d2 = __builtin_amdgcn_mfma_f32_32x32x16_bf16(bf1.s, hf1.s, d2, 0, 0, 0);

            const float wp = out_w[p];                 // s_load
            acc += __builtin_elementwise_max(d2, (f32x16){}) * wp;
        }
    }

    // ---- epilogue (round 7 verbatim): eta[b] = (1/6)*sum_r sW3[o_r]*acc[r] ----
    float etaL = 0.0f;
    if (ihalf == 0) {       // r=0..11 -> o = 0..3, 8..11, 16..19
        #pragma unroll
        for (int r = 0; r < 12; ++r)
            etaL = fmaf(acc[r], sW3[(r & 3) + 8 * (r >> 2)], etaL);
    } else {                // r=0..7 -> o = 4..7, 12..15
        #pragma unroll
        for (int r = 0; r < 8; ++r)
            etaL = fmaf(acc[r], sW3[(r & 3) + 8 * (r >> 2) + 4], etaL);
    }
    etaL += __shfl_xor(etaL, 32, 64);   // combine o-halves
    if (ihalf == 0) atomicAdd(&etab[b], etaL);
    __syncthreads();

    if (tid < kM) {
        float eta = etab[tid] * (1.0f / 6.0f) + biasC[kNPairs * 32];
        eta = fminf(fmaxf(eta, -20.0f), 20.0f);
        const int ob = blockIdx.x * kM + tid;
        out[ob] = __expf(eta) * exposure[ob];
    }
}

extern "C" void kernel_launch(void* const* d_in, const int* in_sizes, int n_in,
                              void* d_out, int out_size, void* d_ws, size_t ws_size,
                              hipStream_t stream) {
    (void)n_in; (void)out_size; (void)ws_size;
    const float* x_cont     = (const float*)d_in[0];
    const int*   x_cat      = (const int*)  d_in[1];
    const float* exposure   = (const float*)d_in[2];
    const float* cont_W1    = (const float*)d_in[3];
    const float* cont_b1    = (const float*)d_in[4];
    const float* cont_W2    = (const float*)d_in[5];
    const float* cont_b2    = (const float*)d_in[6];
    const float* cat_tables = (const float*)d_in[7];
    const float* tokens     = (const float*)d_in[8];
    const float* sW1        = (const float*)d_in[9];
    const float* sb1        = (const float*)d_in[10];
    const float* sW2        = (const float*)d_in[11];
    const float* sb2        = (const float*)d_in[12];
    const float* sW3        = (const float*)d_in[13];
    const float* sb3        = (const float*)d_in[14];
    const float* out_w      = (const float*)d_in[15];
    const float* out_b      = (const float*)d_in[16];

    float* biasC = (float*)d_ws;   // (78*32+1)*4 B

    {
        const int n = kNPairs * 32 + 1;
        pairbias_kernel<<<(n + 255) / 256, 256, 0, stream>>>(
            tokens, sW1, sb1, sb3, out_w, out_b, biasC);
    }

    const int B = in_sizes[2];        // exposure is [B]
    pin_main<<<B / kM, kBlock, 0, stream>>>(
        x_cont, x_cat, exposure, cont_W1, cont_b1, cont_W2, cont_b2,
        cat_tables, sW1, sW2, sb2, sW3, out_w, biasC,
        (float*)d_out);
}